// Round 9
// baseline (955.730 us; speedup 1.0000x reference)
//
#include <hip/hip_runtime.h>
#include <math.h>

// ---------------- model constants ----------------
constexpr int LAYERS = 2;
constexpr int H      = 1024;
constexpr int NH     = 16;
constexpr int HD     = 64;
constexpr int NKV    = 4;
constexpr int KVD    = 256;   // NKV*HD
constexpr int IDIM   = 2816;
constexpr int VOCAB  = 32000;
constexpr int RR     = 64;    // lora rank
constexpr int SEQ    = 512;
constexpr float LORA_SCALE = 0.25f;   // 16/64
constexpr float RMS_EPS    = 1e-6f;

typedef __attribute__((ext_vector_type(8))) __bf16 bf16x8;
typedef __attribute__((ext_vector_type(4))) __bf16 bf16x4;
typedef __attribute__((ext_vector_type(4))) float f32x4;

__device__ __forceinline__ float dot4(float4 a, float4 b) {
    return a.x*b.x + a.y*b.y + a.z*b.z + a.w*b.w;
}

__device__ __forceinline__ bf16x8 pack8(float4 a, float4 b) {
    bf16x8 p;
    p[0] = (__bf16)a.x; p[1] = (__bf16)a.y; p[2] = (__bf16)a.z; p[3] = (__bf16)a.w;
    p[4] = (__bf16)b.x; p[5] = (__bf16)b.y; p[6] = (__bf16)b.z; p[7] = (__bf16)b.w;
    return p;
}

// affine dequant: codebook is linspace -> cb[i] = cb0 + i*slope.
__device__ __forceinline__ bf16x8 dq8a(int4 a, int4 b, float sa, float ba) {
    bf16x8 p;
    p[0] = (__bf16)fmaf((float)a.x, sa, ba); p[1] = (__bf16)fmaf((float)a.y, sa, ba);
    p[2] = (__bf16)fmaf((float)a.z, sa, ba); p[3] = (__bf16)fmaf((float)a.w, sa, ba);
    p[4] = (__bf16)fmaf((float)b.x, sa, ba); p[5] = (__bf16)fmaf((float)b.y, sa, ba);
    p[6] = (__bf16)fmaf((float)b.z, sa, ba); p[7] = (__bf16)fmaf((float)b.w, sa, ba);
    return p;
}

// MFMA A-fragment layout: element (row, k) of a [*, K] bf16 matrix lives at
//   ((row>>4)*(K>>3) + (k>>3))*128 + (row&15)*8 + (k&7)
// so one wave's A-fragment load (lane -> row base+(lane&15), k += (lane>>4)*8)
// is a single fully-coalesced 1KB read: lane offset = lane*16B.
__device__ __forceinline__ size_t frag_off(int row, int k, int K) {
    return (((size_t)(row >> 4) * (size_t)(K >> 3) + (size_t)(k >> 3)) << 7)
         + ((row & 15) << 3) + (k & 7);
}

// ---------------- embedding gather ----------------
__global__ __launch_bounds__(256) void k_embed(const int* __restrict__ ids,
                                               const float* __restrict__ embed,
                                               float* __restrict__ h) {
    int s = blockIdx.x;
    int t = threadIdx.x;
    const float4* src = (const float4*)(embed + (size_t)ids[s] * H);
    float4* dst = (float4*)(h + (size_t)s * H);
    dst[t] = src[t];
}

// ---------------- rmsnorm (fp32 in -> bf16 FRAGMENT-layout out) ----------
__global__ __launch_bounds__(256) void k_rmsnorm(const float* __restrict__ h,
                                                 const float* __restrict__ w,
                                                 __bf16* __restrict__ x) {
    __shared__ float red[4];
    int s = blockIdx.x, t = threadIdx.x;
    float4 a = ((const float4*)(h + (size_t)s * H))[t];
    float ss = a.x*a.x + a.y*a.y + a.z*a.z + a.w*a.w;
    #pragma unroll
    for (int o = 32; o > 0; o >>= 1) ss += __shfl_xor(ss, o, 64);
    if ((t & 63) == 0) red[t >> 6] = ss;
    __syncthreads();
    float tot = red[0] + red[1] + red[2] + red[3];
    float scale = rsqrtf(tot * (1.0f / H) + RMS_EPS);
    float4 wv = ((const float4*)w)[t];
    bf16x4 o4;
    o4[0] = (__bf16)(a.x*scale*wv.x); o4[1] = (__bf16)(a.y*scale*wv.y);
    o4[2] = (__bf16)(a.z*scale*wv.z); o4[3] = (__bf16)(a.w*scale*wv.w);
    *(bf16x4*)&x[frag_off(s, t * 4, H)] = o4;
}

// ---------------- unified fused dequant + LoRA MFMA GEMM ----------------
// y[512, N] (+)= xfrag[512,K] @ dequant(widx,am,cb)^T + LORA_S*(x@lA^T)@lB^T
// 128x128 tile, 4 waves (2x2), wave 64x64 via 4x4 mfma_f32_16x16x32_bf16.
// R9 structure:
//  - A-operand is read fragment-direct from global (frag_off layout, L2-hot,
//    coalesced 1KB/wave-load): NO As LDS -> LDS 48KB (LoRA) / 32KB (plain)
//    -> 3 / 4-5 blocks per CU instead of 2.
//  - B-panel (streamed idx) stays coalesced+LDS-staged (R7 lesson).
//  - non-LoRA (lm_head): depth-2 prefetch (two reg sets) + raw s_barrier
//    with lgkmcnt(0)-only (no vmcnt drain) so loads stay in flight ACROSS
//    barriers (counted-vmcnt pattern). LoRA loops are 2-4 iters: depth-1 +
//    __syncthreads (no loads in flight at barrier -> drain free).
// KSPLIT>1: blockIdx.z picks a K-chunk; epilogue is fp32 atomicAdd.
// GRID RULE: blockIdx.y count MUST be 8*ceil(ntTotal/8) (swizzle groups).
struct GSeg {
    const int* widx; const float* am; const float* lA; const float* lB;
    float* y; int N; int ntiles;
};

template<int NSEG, bool LORA, int EPI, int KSPLIT>
__global__ __launch_bounds__(256) void k_gemm(
    const __bf16* __restrict__ x, const float* __restrict__ cb,
    GSeg s0, GSeg s1, GSeg s2, int K, int ntTotal)
{
    __shared__ __align__(16) __bf16 Bs[2][128][64];
    __shared__ __align__(16) __bf16 La[LORA ? 2 : 1][LORA ? 64 : 1][64];

    // XCD swizzle: id groups of 32 = 8 n-tiles x 4 m-tiles; XCD ~ id%8 = n%8
    const int id = blockIdx.x + (blockIdx.y << 2);
    const int mtile = (id >> 3) & 3;
    int n = ((id >> 5) << 3) + (id & 7);
    if (n >= ntTotal) return;

    const int* widx; const float* am; const float* lA; const float* lB;
    float* y; int N;
    if (NSEG == 1 || n < s0.ntiles) {
        widx=s0.widx; am=s0.am; lA=s0.lA; lB=s0.lB; y=s0.y; N=s0.N;
    } else if (NSEG == 2 || (n - s0.ntiles) < s1.ntiles) {
        n -= s0.ntiles;
        widx=s1.widx; am=s1.am; lA=s1.lA; lB=s1.lB; y=s1.y; N=s1.N;
    } else {
        n -= s0.ntiles + s1.ntiles;
        widx=s2.widx; am=s2.am; lA=s2.lA; lB=s2.lB; y=s2.y; N=s2.N;
    }
    const int sbase = mtile * 128;
    const int nbase = n * 128;
    const int t    = threadIdx.x;
    const int lane = t & 63;
    const int wave = t >> 6;
    const int wm = (wave >> 1) * 64;
    const int wn = (wave & 1) * 64;
    const float cb0  = cb[0];
    const float cbsl = (cb[15] - cb[0]) * (1.0f / 15.0f);
    const int srow = t >> 3;          // 0..31
    const int scol = (t & 7) * 8;     // 0,8,..,56
    const int wsw  = (srow & 7) << 3; // write-side LDS swizzle
    const int rsw  = (lane & 7) << 3; // read-side LDS swizzle
    const int KB   = K >> 6;
    const size_t KC = (size_t)(K >> 3);   // 8-elem chunks per row
    // wave's A-fragment base (global, fragment layout)
    const __bf16* xf = x + (((size_t)((sbase + wm) >> 4) * KC) << 7)
                         + ((lane & 15) << 3);

    int kbLo, kbHi;
    if constexpr (KSPLIT > 1) {
        kbLo = ((int)blockIdx.z * KB) / KSPLIT;
        kbHi = (((int)blockIdx.z + 1) * KB) / KSPLIT;
    } else { kbLo = 0; kbHi = KB; }

    f32x4 acc[4][4];
    f32x4 accl[4][4];
    const f32x4 fz = {0.f, 0.f, 0.f, 0.f};
    #pragma unroll
    for (int i = 0; i < 4; ++i)
        #pragma unroll
        for (int j = 0; j < 4; ++j) { acc[i][j] = fz; if constexpr (LORA) accl[i][j] = fz; }

    // prefetch register sets (B-panel idx + am; LoRA also lA rows)
    int4 piA0[4], piA1[4]; float pamA[4];
    float4 plA0[2], plA1[2];
    int4 piB0[4], piB1[4]; float pamB[4];   // second set: !LORA depth-2 only

    auto LOAD_A = [&](int kb_) {
        const int k0_ = kb_ << 6;
        #pragma unroll
        for (int p = 0; p < 4; ++p) {
            const int row_ = p * 32 + srow;
            const int* ip_ = &widx[(size_t)(nbase + row_) * K + k0_ + scol];
            piA0[p] = ((const int4*)ip_)[0];
            piA1[p] = ((const int4*)ip_)[1];
            pamA[p] = am[(size_t)(nbase + row_) * KB + kb_];
        }
        if constexpr (LORA) {
            #pragma unroll
            for (int p = 0; p < 2; ++p) {
                const float* lp = &lA[(size_t)(p * 32 + srow) * K + k0_ + scol];
                plA0[p] = *(const float4*)lp;
                plA1[p] = *(const float4*)(lp + 4);
            }
        }
    };
    auto LOAD_B2 = [&](int kb_) {          // !LORA only
        const int k0_ = kb_ << 6;
        #pragma unroll
        for (int p = 0; p < 4; ++p) {
            const int row_ = p * 32 + srow;
            const int* ip_ = &widx[(size_t)(nbase + row_) * K + k0_ + scol];
            piB0[p] = ((const int4*)ip_)[0];
            piB1[p] = ((const int4*)ip_)[1];
            pamB[p] = am[(size_t)(nbase + row_) * KB + kb_];
        }
    };
    auto STAGE_A = [&](int wb) {
        #pragma unroll
        for (int p = 0; p < 4; ++p) {
            int row = p * 32 + srow;
            float sa = cbsl * pamA[p], ba = cb0 * pamA[p];
            *(bf16x8*)&Bs[wb][row][scol ^ wsw] = dq8a(piA0[p], piA1[p], sa, ba);
        }
        if constexpr (LORA) {
            #pragma unroll
            for (int p = 0; p < 2; ++p)
                *(bf16x8*)&La[wb][p * 32 + srow][scol ^ wsw] = pack8(plA0[p], plA1[p]);
        }
    };
    auto STAGE_B2 = [&](int wb) {          // !LORA only
        #pragma unroll
        for (int p = 0; p < 4; ++p) {
            int row = p * 32 + srow;
            float sa = cbsl * pamB[p], ba = cb0 * pamB[p];
            *(bf16x8*)&Bs[wb][row][scol ^ wsw] = dq8a(piB0[p], piB1[p], sa, ba);
        }
    };
    auto MFMAP = [&](int bufi, int kb_) {
        #pragma unroll
        for (int s = 0; s < 2; ++s) {
            bf16x8 a[4], b[4];
            #pragma unroll
            for (int mi = 0; mi < 4; ++mi)
                a[mi] = *(const bf16x8*)&xf[
                    ((size_t)mi * KC + (size_t)((kb_ << 3) + s * 4 + (lane >> 4))) << 7];
            #pragma unroll
            for (int ni = 0; ni < 4; ++ni)
                b[ni] = *(bf16x8*)&Bs[bufi][wn + ni*16 + (lane & 15)][(s*32 + (lane >> 4)*8) ^ rsw];
            #pragma unroll
            for (int mi = 0; mi < 4; ++mi)
                #pragma unroll
                for (int ni = 0; ni < 4; ++ni)
                    acc[mi][ni] = __builtin_amdgcn_mfma_f32_16x16x32_bf16(
                        a[mi], b[ni], acc[mi][ni], 0, 0, 0);
            if constexpr (LORA) {
                bf16x8 bl[4];
                #pragma unroll
                for (int ni = 0; ni < 4; ++ni)
                    bl[ni] = *(bf16x8*)&La[bufi][ni*16 + (lane & 15)][(s*32 + (lane >> 4)*8) ^ rsw];
                #pragma unroll
                for (int mi = 0; mi < 4; ++mi)
                    #pragma unroll
                    for (int ni = 0; ni < 4; ++ni)
                        accl[mi][ni] = __builtin_amdgcn_mfma_f32_16x16x32_bf16(
                            a[mi], bl[ni], accl[mi][ni], 0, 0, 0);
            }
        }
    };

    if constexpr (!LORA) {
        // depth-2 pipeline with counted-vmcnt barriers: lgkmcnt(0) only,
        // global loads stay in flight across the raw s_barrier.
        LOAD_A(kbLo);
        if (kbLo + 1 < kbHi) LOAD_B2(kbLo + 1);
        STAGE_A(0);
        asm volatile("s_waitcnt lgkmcnt(0)" ::: "memory");
        __builtin_amdgcn_s_barrier();
        int cur = 0;
        for (int kb = kbLo; kb < kbHi; ++kb, cur ^= 1) {
            const bool evenIt = ((kb - kbLo) & 1) == 0;
            if (kb + 2 < kbHi) { if (evenIt) LOAD_A(kb + 2); else LOAD_B2(kb + 2); }
            MFMAP(cur, kb);
            if (kb + 1 < kbHi) { if (evenIt) STAGE_B2(cur ^ 1); else STAGE_A(cur ^ 1); }
            asm volatile("s_waitcnt lgkmcnt(0)" ::: "memory");
            __builtin_amdgcn_s_barrier();
        }
    } else {
        // depth-1 (loops are 2-4 iters; loads consumed in-iter -> plain sync)
        LOAD_A(kbLo);
        STAGE_A(0);
        __syncthreads();
        int cur = 0;
        for (int kb = kbLo; kb < kbHi; ++kb, cur ^= 1) {
            if (kb + 1 < kbHi) LOAD_A(kb + 1);
            MFMAP(cur, kb);
            if (kb + 1 < kbHi) STAGE_A(cur ^ 1);
            __syncthreads();
        }
    }

    if constexpr (LORA) {
        // lt (C/D layout, waves with wn==0 own unique rows) -> Bs[1] as bf16
        if (wn == 0) {
            const int cr = (lane >> 4) * 4, cc = lane & 15;
            #pragma unroll
            for (int mi = 0; mi < 4; ++mi)
                #pragma unroll
                for (int ni = 0; ni < 4; ++ni)
                    #pragma unroll
                    for (int r = 0; r < 4; ++r) {
                        int row = wm + mi*16 + cr + r;
                        Bs[1][row][(ni*16 + cc) ^ ((row & 7) << 3)] =
                            (__bf16)(LORA_SCALE * accl[mi][ni][r]);
                    }
        }
        #pragma unroll
        for (int p = 0; p < 4; ++p) {   // Bm tile [128][64] -> Bs[0]
            int row = p * 32 + srow;
            const float* bp = &lB[(size_t)(nbase + row) * RR + scol];
            *(bf16x8*)&Bs[0][row][scol ^ wsw] = pack8(*(const float4*)bp, *(const float4*)(bp + 4));
        }
        __syncthreads();
        #pragma unroll
        for (int s = 0; s < 2; ++s) {
            bf16x8 a[4], b[4];
            #pragma unroll
            for (int mi = 0; mi < 4; ++mi)
                a[mi] = *(bf16x8*)&Bs[1][wm + mi*16 + (lane & 15)][(s*32 + (lane >> 4)*8) ^ rsw];
            #pragma unroll
            for (int ni = 0; ni < 4; ++ni)
                b[ni] = *(bf16x8*)&Bs[0][wn + ni*16 + (lane & 15)][(s*32 + (lane >> 4)*8) ^ rsw];
            #pragma unroll
            for (int mi = 0; mi < 4; ++mi)
                #pragma unroll
                for (int ni = 0; ni < 4; ++ni)
                    acc[mi][ni] = __builtin_amdgcn_mfma_f32_16x16x32_bf16(
                        a[mi], b[ni], acc[mi][ni], 0, 0, 0);
        }
    }

    // epilogue: C/D layout col=lane&15, row=(lane>>4)*4+reg
    const int cr = (lane >> 4) * 4;
    const int cc = lane & 15;
    #pragma unroll
    for (int mi = 0; mi < 4; ++mi) {
        #pragma unroll
        for (int ni = 0; ni < 4; ++ni) {
            int gr = sbase + wm + mi * 16 + cr;
            int gc = nbase + wn + ni * 16 + cc;
            #pragma unroll
            for (int r = 0; r < 4; ++r) {
                size_t off = (size_t)(gr + r) * N + gc;
                if constexpr (EPI == 0) {
                    if constexpr (KSPLIT > 1) atomicAdd(&y[off], acc[mi][ni][r]);
                    else                      y[off] = acc[mi][ni][r];
                }
                if constexpr (EPI == 1) {
                    if constexpr (KSPLIT > 1) atomicAdd(&y[off], acc[mi][ni][r]);
                    else                      y[off] += acc[mi][ni][r];
                }
            }
        }
    }
}

// ---------------- silu(gate) * up -> bf16 FRAGMENT layout ----------------
__global__ __launch_bounds__(256) void k_silu(const float* __restrict__ g,
                                              const float* __restrict__ u,
                                              __bf16* __restrict__ out) {
    int row = blockIdx.x;
    int t = threadIdx.x;
    const float4* gr = (const float4*)(g + (size_t)row * IDIM);
    const float4* ur = (const float4*)(u + (size_t)row * IDIM);
    for (int j = t; j < IDIM / 4; j += 256) {
        float4 gv = gr[j];
        float4 uv = ur[j];
        bf16x4 o4;
        o4[0] = (__bf16)(gv.x / (1.f + __expf(-gv.x)) * uv.x);
        o4[1] = (__bf16)(gv.y / (1.f + __expf(-gv.y)) * uv.y);
        o4[2] = (__bf16)(gv.z / (1.f + __expf(-gv.z)) * uv.z);
        o4[3] = (__bf16)(gv.w / (1.f + __expf(-gv.w)) * uv.w);
        *(bf16x4*)&out[frag_off(row, j * 4, IDIM)] = o4;
    }
}

// ---------------- RoPE (rotate-half) on q and k in place ----------------
__global__ __launch_bounds__(256) void k_rope(float* __restrict__ q, float* __restrict__ k) {
    int s  = blockIdx.x;
    int hs = blockIdx.y * 4 + (threadIdx.x >> 6);   // 0..19
    int d  = threadIdx.x & 63;
    float* p = (hs < NH) ? q + ((size_t)s * NH + hs) * HD
                         : k + ((size_t)s * NKV + (hs - NH)) * HD;
    int j = d & 31;
    float inv = exp2f(-(float)(2 * j) * (13.287712379549449f / 64.0f));
    float ang = (float)s * inv;
    float sn, c;
    __sincosf(ang, &sn, &c);
    float xv = p[d];
    float other = (d < 32) ? -p[d + 32] : p[d - 32];   // wave-lockstep safe
    p[d] = xv * c + other * sn;
}

// ---------------- attention scores + causal softmax ----------------
__global__ __launch_bounds__(256) void k_scores(const float* __restrict__ q,
                                                const float* __restrict__ k,
                                                float* __restrict__ attn) {
    int qt = blockIdx.x;
    int h  = blockIdx.y;
    int kvh = h >> 2;
    __shared__ float qs[16][68];
    __shared__ float ks[64][68];
    __shared__ float sc[16][528];
    int t = threadIdx.x;
    { int row = t >> 4; int c4 = (t & 15) << 2;
      *(float4*)&qs[row][c4] = *(const float4*)&q[(size_t)(qt*16 + row) * H + h * HD + c4]; }
    const int cmax = (qt * 16 + 15) >> 6;
    for (int c = 0; c <= cmax; ++c) {
        #pragma unroll
        for (int i = 0; i < 4; ++i) {
            int id = t + i * 256; int row = id >> 4; int c4 = (id & 15) << 2;
            *(float4*)&ks[row][c4] = *(const float4*)&k[(size_t)(c*64 + row) * KVD + kvh * HD + c4];
        }
        __syncthreads();
        int r  = t >> 4;
        int cc = (t & 15) << 2;
        float4 acc = make_float4(0.f, 0.f, 0.f, 0.f);
        #pragma unroll
        for (int kk = 0; kk < 64; kk += 4) {
            float4 a = *(const float4*)&qs[r][kk];
            acc.x += dot4(a, *(const float4*)&ks[cc + 0][kk]);
            acc.y += dot4(a, *(const float4*)&ks[cc + 1][kk]);
            acc.z += dot4(a, *(const float4*)&ks[cc + 2][kk]);
            acc.w += dot4(a, *(const float4*)&ks[cc + 3][kk]);
        }
        acc.x *= 0.125f; acc.y *= 0.125f; acc.z *= 0.125f; acc.w *= 0.125f;
        *(float4*)&sc[r][c * 64 + cc] = acc;
        __syncthreads();
    }
    int r = t >> 4, lane = t & 15;
    int qpos = qt * 16 + r;
    float mx = -1e30f;
    for (int c = lane; c <= qpos; c += 16) mx = fmaxf(mx, sc[r][c]);
    #pragma unroll
    for (int o = 8; o > 0; o >>= 1) mx = fmaxf(mx, __shfl_xor(mx, o, 16));
    float sum = 0.f;
    for (int c = lane; c <= qpos; c += 16) {
        float e = __expf(sc[r][c] - mx);
        sc[r][c] = e; sum += e;
    }
    #pragma unroll
    for (int o = 8; o > 0; o >>= 1) sum += __shfl_xor(sum, o, 16);
    float inv = 1.0f / sum;
    for (int c = lane; c < SEQ; c += 16)
        attn[((size_t)h * SEQ + qpos) * SEQ + c] = (c <= qpos) ? sc[r][c] * inv : 0.f;
}

// ---------------- ctx = attn @ v -> bf16 FRAGMENT layout ------------------
__global__ __launch_bounds__(256) void k_ctx(const float* __restrict__ attn,
                                             const float* __restrict__ v,
                                             __bf16* __restrict__ ctx) {
    int qt = blockIdx.x, h = blockIdx.y, kvh = h >> 2;
    __shared__ float as_[16][68];
    __shared__ float vs[64][68];
    int t = threadIdx.x;
    int row = t >> 4;
    int col = (t & 15) * 4;
    float acc0 = 0.f, acc1 = 0.f, acc2 = 0.f, acc3 = 0.f;
    const int cmax = (qt * 16 + 15) >> 6;
    for (int c = 0; c <= cmax; ++c) {
        { int r2 = t >> 4; int c4 = (t & 15) << 2;
          *(float4*)&as_[r2][c4] = *(const float4*)&attn[((size_t)h*SEQ + qt*16 + r2) * SEQ + c*64 + c4]; }
        #pragma unroll
        for (int i = 0; i < 4; ++i) {
            int id = t + i * 256; int r2 = id >> 4; int c4 = (id & 15) << 2;
            *(float4*)&vs[r2][c4] = *(const float4*)&v[(size_t)(c*64 + r2) * KVD + kvh * HD + c4];
        }
        __syncthreads();
        #pragma unroll 16
        for (int kk = 0; kk < 64; ++kk) {
            float a = as_[row][kk];
            float4 b = *(const float4*)&vs[kk][col];
            acc0 += a * b.x; acc1 += a * b.y; acc2 += a * b.z; acc3 += a * b.w;
        }
        __syncthreads();
    }
    bf16x4 o4;
    o4[0] = (__bf16)acc0; o4[1] = (__bf16)acc1;
    o4[2] = (__bf16)acc2; o4[3] = (__bf16)acc3;
    *(bf16x4*)&ctx[frag_off(qt*16 + row, h * HD + col, H)] = o4;
}

// ---------------- host launcher ----------------
extern "C" void kernel_launch(void* const* d_in, const int* in_sizes, int n_in,
                              void* d_out, int out_size, void* d_ws, size_t ws_size,
                              hipStream_t stream) {
    const int*   p_ids   = (const int*)  d_in[0];
    const float* p_embed = (const float*)d_in[1];
    const float* p_cb    = (const float*)d_in[2];
    const int*   p_qidx  = (const int*)  d_in[3];  const float* p_qam = (const float*)d_in[4];
    const float* p_qA    = (const float*)d_in[5];  const float* p_qB  = (const float*)d_in[6];
    const int*   p_kidx  = (const int*)  d_in[7];  const float* p_kam = (const float*)d_in[8];
    const float* p_kA    = (const float*)d_in[9];  const float* p_kB  = (const float*)d_in[10];
    const int*   p_vidx  = (const int*)  d_in[11]; const float* p_vam = (const float*)d_in[12];
    const float* p_vA    = (const float*)d_in[13]; const float* p_vB  = (const float*)d_in[14];
    const int*   p_oidx  = (const int*)  d_in[15]; const float* p_oam = (const float*)d_in[16];
    const float* p_oA    = (const float*)d_in[17]; const float* p_oB  = (const float*)d_in[18];
    const int*   p_gidx  = (const int*)  d_in[19]; const float* p_gam = (const float*)d_in[20];
    const float* p_gA    = (const float*)d_in[21]; const float* p_gB  = (const float*)d_in[22];
    const int*   p_uidx  = (const int*)  d_in[23]; const float* p_uam = (const float*)d_in[24];
    const float* p_uA    = (const float*)d_in[25]; const float* p_uB  = (const float*)d_in[26];
    const int*   p_didx  = (const int*)  d_in[27]; const float* p_dam = (const float*)d_in[28];
    const float* p_dA    = (const float*)d_in[29]; const float* p_dB  = (const float*)d_in[30];
    const float* p_ln1   = (const float*)d_in[31];
    const float* p_ln2   = (const float*)d_in[32];
    const float* p_fn    = (const float*)d_in[33];
    const int*   p_lmidx = (const int*)  d_in[34]; const float* p_lmam = (const float*)d_in[35];

    char* w = (char*)d_ws;
    const size_t MB = 1024 * 1024;
    float*  hbuf  = (float*) (w + 0);          // 512x1024 f32  (2 MB)
    __bf16* xb16  = (__bf16*)(w + 2*MB);       // 512x1024 bf16 frag (1 MB)
    float*  qb    = (float*) (w + 3*MB);       // 512x1024 f32  (2 MB)
    float*  kb    = (float*) (w + 5*MB);       // 512x256  f32  (0.5 MB)
    float*  vb    = (float*) (w + 5*MB + 512*1024);  // 512x256 f32 (0.5 MB)
    __bf16* ctx16 = (__bf16*)(w + 6*MB);       // 512x1024 bf16 frag (1 MB)
    float*  attn  = (float*) (w + 7*MB);       // 16x512x512 f32 (16.8 MB)
    __bf16* g16   = (__bf16*)(w + 7*MB);       // alias: 512x2816 bf16 frag (2.9 MB)
    float*  gatef = (float*) (w + 11*MB);      // alias: 512x2816 f32 (5.5 MB)
    float*  upf   = gatef + (size_t)SEQ*IDIM;  // contiguous: 512x2816 f32

    const GSeg znull = {nullptr, nullptr, nullptr, nullptr, nullptr, 0, 0};
    const size_t mlpB = (size_t)SEQ * IDIM * sizeof(float);

    k_embed<<<SEQ, 256, 0, stream>>>(p_ids, p_embed, hbuf);

    for (int l = 0; l < LAYERS; ++l) {
        const int*   qi  = p_qidx + (size_t)l * H * H;      const float* qa = p_qam + (size_t)l * (H*H/64);
        const float* qAl = p_qA + (size_t)l * RR * H;       const float* qBl = p_qB + (size_t)l * H * RR;
        const int*   ki  = p_kidx + (size_t)l * KVD * H;    const float* ka = p_kam + (size_t)l * (KVD*H/64);
        const float* kAl = p_kA + (size_t)l * RR * H;       const float* kBl = p_kB + (size_t)l * KVD * RR;
        const int*   vi  = p_vidx + (size_t)l * KVD * H;    const float* va = p_vam + (size_t)l * (KVD*H/64);
        const float* vAl = p_vA + (size_t)l * RR * H;       const float* vBl = p_vB + (size_t)l * KVD * RR;
        const int*   oi  = p_oidx + (size_t)l * H * H;      const float* oa = p_oam + (size_t)l * (H*H/64);
        const float* oAl = p_oA + (size_t)l * RR * H;       const float* oBl = p_oB + (size_t)l * H * RR;
        const int*   gi  = p_gidx + (size_t)l * IDIM * H;   const float* ga = p_gam + (size_t)l * (IDIM*H/64);
        const float* gAl = p_gA + (size_t)l * RR * H;       const float* gBl = p_gB + (size_t)l * IDIM * RR;
        const int*   ui  = p_uidx + (size_t)l * IDIM * H;   const float* ua = p_uam + (size_t)l * (IDIM*H/64);
        const float* uAl = p_uA + (size_t)l * RR * H;       const float* uBl = p_uB + (size_t)l * IDIM * RR;
        const int*   di  = p_didx + (size_t)l * H * IDIM;   const float* da = p_dam + (size_t)l * (H*IDIM/64);
        const float* dAl = p_dA + (size_t)l * RR * IDIM;    const float* dBl = p_dB + (size_t)l * H * RR;

        // ---- attention block ----
        k_rmsnorm<<<SEQ, 256, 0, stream>>>(hbuf, p_ln1 + (size_t)l * H, xb16);
        hipMemsetAsync(qb, 0, 3*MB, stream);   // qb+kb+vb contiguous
        {
            GSeg sq = {qi, qa, qAl, qBl, qb, H,   8};
            GSeg sk = {ki, ka, kAl, kBl, kb, KVD, 2};
            GSeg sv = {vi, va, vAl, vBl, vb, KVD, 2};
            k_gemm<3,true,0,8><<<dim3(4,16,8), 256, 0, stream>>>(
                xb16, p_cb, sq, sk, sv, H, 12);
        }
        k_rope<<<dim3(SEQ, 5), 256, 0, stream>>>(qb, kb);
        k_scores<<<dim3(SEQ/16, NH), 256, 0, stream>>>(qb, kb, attn);
        k_ctx<<<dim3(SEQ/16, NH), 256, 0, stream>>>(attn, vb, ctx16);
        {
            GSeg so = {oi, oa, oAl, oBl, hbuf, H, 8};
            k_gemm<1,true,1,8><<<dim3(4,8,8), 256, 0, stream>>>(
                ctx16, p_cb, so, znull, znull, H, 8);
        }

        // ---- MLP block ----
        k_rmsnorm<<<SEQ, 256, 0, stream>>>(hbuf, p_ln2 + (size_t)l * H, xb16);
        hipMemsetAsync(gatef, 0, 2 * mlpB, stream);   // gate+up contiguous
        {
            GSeg sg = {gi, ga, gAl, gBl, gatef, IDIM, 22};
            GSeg su = {ui, ua, uAl, uBl, upf,   IDIM, 22};
            // grid-y = 48 = 8*ceil(44/8): swizzle groups must be complete!
            k_gemm<2,true,0,4><<<dim3(4,48,4), 256, 0, stream>>>(
                xb16, p_cb, sg, su, znull, H, 44);
        }
        k_silu<<<SEQ, 256, 0, stream>>>(gatef, upf, g16);
        {
            GSeg sd = {di, da, dAl, dBl, hbuf, H, 8};
            k_gemm<1,true,1,11><<<dim3(4,8,11), 256, 0, stream>>>(
                g16, p_cb, sd, znull, znull, IDIM, 8);
        }
    }

    // final norm + quantized lm_head (no LoRA): LDS-staged B, frag-direct A,
    // depth-2 prefetch + counted-vmcnt barriers.
    k_rmsnorm<<<SEQ, 256, 0, stream>>>(hbuf, p_fn, xb16);
    {
        GSeg sl = {p_lmidx, p_lmam, nullptr, nullptr, (float*)d_out, VOCAB, 250};
        k_gemm<1,false,0,1><<<dim3(4,256), 256, 0, stream>>>(
            xb16, p_cb, sl, znull, znull, H, 250);
    }
}

// Round 12
// 877.815 us; speedup vs baseline: 1.0888x; 1.0888x over previous
//
#include <hip/hip_runtime.h>
#include <math.h>

// ---------------- model constants ----------------
constexpr int LAYERS = 2;
constexpr int H      = 1024;
constexpr int NH     = 16;
constexpr int HD     = 64;
constexpr int NKV    = 4;
constexpr int KVD    = 256;   // NKV*HD
constexpr int IDIM   = 2816;
constexpr int VOCAB  = 32000;
constexpr int RR     = 64;    // lora rank
constexpr int SEQ    = 512;
constexpr float LORA_SCALE = 0.25f;   // 16/64
constexpr float RMS_EPS    = 1e-6f;

typedef __attribute__((ext_vector_type(8))) __bf16 bf16x8;
typedef __attribute__((ext_vector_type(4))) __bf16 bf16x4;
typedef __attribute__((ext_vector_type(4))) float f32x4;

__device__ __forceinline__ float dot4(float4 a, float4 b) {
    return a.x*b.x + a.y*b.y + a.z*b.z + a.w*b.w;
}

__device__ __forceinline__ bf16x8 pack8(float4 a, float4 b) {
    bf16x8 p;
    p[0] = (__bf16)a.x; p[1] = (__bf16)a.y; p[2] = (__bf16)a.z; p[3] = (__bf16)a.w;
    p[4] = (__bf16)b.x; p[5] = (__bf16)b.y; p[6] = (__bf16)b.z; p[7] = (__bf16)b.w;
    return p;
}

// affine dequant: codebook is linspace -> cb[i] = cb0 + i*slope.
__device__ __forceinline__ bf16x8 dq8a(int4 a, int4 b, float sa, float ba) {
    bf16x8 p;
    p[0] = (__bf16)fmaf((float)a.x, sa, ba); p[1] = (__bf16)fmaf((float)a.y, sa, ba);
    p[2] = (__bf16)fmaf((float)a.z, sa, ba); p[3] = (__bf16)fmaf((float)a.w, sa, ba);
    p[4] = (__bf16)fmaf((float)b.x, sa, ba); p[5] = (__bf16)fmaf((float)b.y, sa, ba);
    p[6] = (__bf16)fmaf((float)b.z, sa, ba); p[7] = (__bf16)fmaf((float)b.w, sa, ba);
    return p;
}

// ---------------- embedding gather ----------------
__global__ __launch_bounds__(256) void k_embed(const int* __restrict__ ids,
                                               const float* __restrict__ embed,
                                               float* __restrict__ h) {
    int s = blockIdx.x;
    int t = threadIdx.x;
    const float4* src = (const float4*)(embed + (size_t)ids[s] * H);
    float4* dst = (float4*)(h + (size_t)s * H);
    dst[t] = src[t];
}

// ---------------- rmsnorm (fp32 in -> bf16 out, row-major) ----------------
__global__ __launch_bounds__(256) void k_rmsnorm(const float* __restrict__ h,
                                                 const float* __restrict__ w,
                                                 __bf16* __restrict__ x) {
    __shared__ float red[4];
    int s = blockIdx.x, t = threadIdx.x;
    float4 a = ((const float4*)(h + (size_t)s * H))[t];
    float ss = a.x*a.x + a.y*a.y + a.z*a.z + a.w*a.w;
    #pragma unroll
    for (int o = 32; o > 0; o >>= 1) ss += __shfl_xor(ss, o, 64);
    if ((t & 63) == 0) red[t >> 6] = ss;
    __syncthreads();
    float tot = red[0] + red[1] + red[2] + red[3];
    float scale = rsqrtf(tot * (1.0f / H) + RMS_EPS);
    float4 wv = ((const float4*)w)[t];
    bf16x4 o4;
    o4[0] = (__bf16)(a.x*scale*wv.x); o4[1] = (__bf16)(a.y*scale*wv.y);
    o4[2] = (__bf16)(a.z*scale*wv.z); o4[3] = (__bf16)(a.w*scale*wv.w);
    *(bf16x4*)&x[(size_t)s * H + t * 4] = o4;
}

// ---------------- unified fused dequant + LoRA MFMA GEMM ----------------
// y[512, N] (+)= x16[512,K] @ dequant(widx,am,cb)^T + LORA_S*(x@lA^T)@lB^T
// R10 geometry: 128x128 tile, 512 threads / 8 waves (2m x 4n), wave tile
// 64x32 -> acc[4][2] = 32 AGPR (was 64). The occupancy limiter since R2
// has been total regs (~168 > 128-tier -> 8 waves/CU = 25% cap); halving
// acc + prefetch sets targets the <=128 tier -> 16 waves/CU for non-LoRA
// (enforced by launch_bounds min-waves=4). LoRA keeps min-waves=2.
// k-loop (R6, verified): LOADT(kb+1) first, MFMA(cur), STAGE(cur^1), sync.
// LDS XOR-swizzle (col ^= (row&7)<<3) keeps ds_read_b128 conflict-free.
// LoRA accl: waves with wn<64 each own a 32-wide slice of the 64 lora cols.
// KSPLIT>1: blockIdx.z picks a K-chunk; epilogue is fp32 atomicAdd.
// GRID RULE: blockIdx.y count MUST be 8*ceil(ntTotal/8) (swizzle groups).
struct GSeg {
    const int* widx; const float* am; const float* lA; const float* lB;
    float* y; int N; int ntiles;
};

template<int NSEG, bool LORA, int EPI, int KSPLIT>
__global__ __launch_bounds__(512, LORA ? 2 : 4) void k_gemm(
    const __bf16* __restrict__ x, const float* __restrict__ cb,
    GSeg s0, GSeg s1, GSeg s2, int K, int ntTotal)
{
    __shared__ __align__(16) __bf16 As[2][128][64];
    __shared__ __align__(16) __bf16 Bs[2][128][64];
    __shared__ __align__(16) __bf16 La[LORA ? 2 : 1][LORA ? 64 : 1][64];

    // XCD swizzle: id groups of 32 = 8 n-tiles x 4 m-tiles; XCD ~ id%8 = n%8
    const int id = blockIdx.x + (blockIdx.y << 2);
    const int mtile = (id >> 3) & 3;
    int n = ((id >> 5) << 3) + (id & 7);
    if (n >= ntTotal) return;

    const int* widx; const float* am; const float* lA; const float* lB;
    float* y; int N;
    if (NSEG == 1 || n < s0.ntiles) {
        widx=s0.widx; am=s0.am; lA=s0.lA; lB=s0.lB; y=s0.y; N=s0.N;
    } else if (NSEG == 2 || (n - s0.ntiles) < s1.ntiles) {
        n -= s0.ntiles;
        widx=s1.widx; am=s1.am; lA=s1.lA; lB=s1.lB; y=s1.y; N=s1.N;
    } else {
        n -= s0.ntiles + s1.ntiles;
        widx=s2.widx; am=s2.am; lA=s2.lA; lB=s2.lB; y=s2.y; N=s2.N;
    }
    const int sbase = mtile * 128;
    const int nbase = n * 128;
    const int t    = threadIdx.x;          // 0..511
    const int lane = t & 63;
    const int wave = t >> 6;               // 0..7
    const int wm = (wave >> 2) * 64;       // 0,64
    const int wn = (wave & 3) * 32;        // 0,32,64,96
    const float cb0  = cb[0];
    const float cbsl = (cb[15] - cb[0]) * (1.0f / 15.0f);
    const int srow = t >> 3;               // 0..63
    const int scol = (t & 7) * 8;          // 0,8,..,56
    const int wsw  = (srow & 7) << 3;      // write-side LDS swizzle
    const int rsw  = (lane & 7) << 3;      // read-side LDS swizzle
    const int KB   = K >> 6;

    int kbLo, kbHi;
    if constexpr (KSPLIT > 1) {
        kbLo = ((int)blockIdx.z * KB) / KSPLIT;
        kbHi = (((int)blockIdx.z + 1) * KB) / KSPLIT;
    } else { kbLo = 0; kbHi = KB; }

    f32x4 acc[4][2];
    f32x4 accl[4][2];
    const f32x4 fz = {0.f, 0.f, 0.f, 0.f};
    #pragma unroll
    for (int i = 0; i < 4; ++i)
        #pragma unroll
        for (int j = 0; j < 2; ++j) { acc[i][j] = fz; if constexpr (LORA) accl[i][j] = fz; }

    // prefetch registers (halved vs 256-thread version)
    bf16x8 pa[2]; int4 pi0[2], pi1[2]; float pam[2];
    float4 pl0, pl1;
    auto LOADT = [&](int kb_) {
        const int k0_ = kb_ << 6;
        #pragma unroll
        for (int p = 0; p < 2; ++p) {
            const int row_ = p * 64 + srow;
            pa[p] = *(const bf16x8*)&x[(size_t)(sbase + row_) * K + k0_ + scol];
            const int* ip_ = &widx[(size_t)(nbase + row_) * K + k0_ + scol];
            pi0[p] = ((const int4*)ip_)[0];
            pi1[p] = ((const int4*)ip_)[1];
            pam[p] = am[(size_t)(nbase + row_) * KB + kb_];
        }
        if constexpr (LORA) {
            const float* lp = &lA[(size_t)srow * K + k0_ + scol];
            pl0 = *(const float4*)lp;
            pl1 = *(const float4*)(lp + 4);
        }
    };
    auto STAGE = [&](int wb) {
        #pragma unroll
        for (int p = 0; p < 2; ++p) {
            int row = p * 64 + srow;
            *(bf16x8*)&As[wb][row][scol ^ wsw] = pa[p];
            float sa = cbsl * pam[p], ba = cb0 * pam[p];
            *(bf16x8*)&Bs[wb][row][scol ^ wsw] = dq8a(pi0[p], pi1[p], sa, ba);
        }
        if constexpr (LORA)
            *(bf16x8*)&La[wb][srow][scol ^ wsw] = pack8(pl0, pl1);
    };

    LOADT(kbLo);
    STAGE(0);
    __syncthreads();

    int cur = 0;
    for (int kb = kbLo; kb < kbHi; ++kb, cur ^= 1) {
        if (kb + 1 < kbHi) LOADT(kb + 1);   // issue EARLY: MFMA phase covers latency
        #pragma unroll
        for (int s = 0; s < 2; ++s) {
            bf16x8 a[4], b[2];
            #pragma unroll
            for (int mi = 0; mi < 4; ++mi)
                a[mi] = *(bf16x8*)&As[cur][wm + mi*16 + (lane & 15)][(s*32 + (lane >> 4)*8) ^ rsw];
            #pragma unroll
            for (int ni = 0; ni < 2; ++ni)
                b[ni] = *(bf16x8*)&Bs[cur][wn + ni*16 + (lane & 15)][(s*32 + (lane >> 4)*8) ^ rsw];
            #pragma unroll
            for (int mi = 0; mi < 4; ++mi)
                #pragma unroll
                for (int ni = 0; ni < 2; ++ni)
                    acc[mi][ni] = __builtin_amdgcn_mfma_f32_16x16x32_bf16(
                        a[mi], b[ni], acc[mi][ni], 0, 0, 0);
            if constexpr (LORA) {
                if (wn < 64) {   // this wave owns lora cols wn..wn+31
                    bf16x8 bl[2];
                    #pragma unroll
                    for (int ni = 0; ni < 2; ++ni)
                        bl[ni] = *(bf16x8*)&La[cur][wn + ni*16 + (lane & 15)][(s*32 + (lane >> 4)*8) ^ rsw];
                    #pragma unroll
                    for (int mi = 0; mi < 4; ++mi)
                        #pragma unroll
                        for (int ni = 0; ni < 2; ++ni)
                            accl[mi][ni] = __builtin_amdgcn_mfma_f32_16x16x32_bf16(
                                a[mi], bl[ni], accl[mi][ni], 0, 0, 0);
                }
            }
        }
        if (kb + 1 < kbHi) STAGE(cur ^ 1);  // consume regs (waits happened under MFMA)
        __syncthreads();
    }

    if constexpr (LORA) {
        // lt (C/D layout): waves wn<64 write rows wm..wm+63 x lora cols
        // wn..wn+31 into As[0] (disjoint across the 4 participating waves)
        if (wn < 64) {
            const int cr = (lane >> 4) * 4, cc = lane & 15;
            #pragma unroll
            for (int mi = 0; mi < 4; ++mi)
                #pragma unroll
                for (int ni = 0; ni < 2; ++ni)
                    #pragma unroll
                    for (int r = 0; r < 4; ++r) {
                        int row = wm + mi*16 + cr + r;
                        As[0][row][(wn + ni*16 + cc) ^ ((row & 7) << 3)] =
                            (__bf16)(LORA_SCALE * accl[mi][ni][r]);
                    }
        }
        #pragma unroll
        for (int p = 0; p < 2; ++p) {   // Bm tile [128][64] -> Bs[0]
            int row = p * 64 + srow;
            const float* bp = &lB[(size_t)(nbase + row) * RR + scol];
            *(bf16x8*)&Bs[0][row][scol ^ wsw] = pack8(*(const float4*)bp, *(const float4*)(bp + 4));
        }
        __syncthreads();
        #pragma unroll
        for (int s = 0; s < 2; ++s) {
            bf16x8 a[4], b[2];
            #pragma unroll
            for (int mi = 0; mi < 4; ++mi)
                a[mi] = *(bf16x8*)&As[0][wm + mi*16 + (lane & 15)][(s*32 + (lane >> 4)*8) ^ rsw];
            #pragma unroll
            for (int ni = 0; ni < 2; ++ni)
                b[ni] = *(bf16x8*)&Bs[0][wn + ni*16 + (lane & 15)][(s*32 + (lane >> 4)*8) ^ rsw];
            #pragma unroll
            for (int mi = 0; mi < 4; ++mi)
                #pragma unroll
                for (int ni = 0; ni < 2; ++ni)
                    acc[mi][ni] = __builtin_amdgcn_mfma_f32_16x16x32_bf16(
                        a[mi], b[ni], acc[mi][ni], 0, 0, 0);
        }
    }

    // epilogue: C/D layout col=lane&15, row=(lane>>4)*4+reg
    const int cr = (lane >> 4) * 4;
    const int cc = lane & 15;
    #pragma unroll
    for (int mi = 0; mi < 4; ++mi) {
        #pragma unroll
        for (int ni = 0; ni < 2; ++ni) {
            int gr = sbase + wm + mi * 16 + cr;
            int gc = nbase + wn + ni * 16 + cc;
            #pragma unroll
            for (int r = 0; r < 4; ++r) {
                size_t off = (size_t)(gr + r) * N + gc;
                if constexpr (EPI == 0) {
                    if constexpr (KSPLIT > 1) atomicAdd(&y[off], acc[mi][ni][r]);
                    else                      y[off] = acc[mi][ni][r];
                }
                if constexpr (EPI == 1) {
                    if constexpr (KSPLIT > 1) atomicAdd(&y[off], acc[mi][ni][r]);
                    else                      y[off] += acc[mi][ni][r];
                }
            }
        }
    }
}

// ---------------- silu(gate) * up -> bf16 ----------------
__global__ __launch_bounds__(256) void k_silu(const float* __restrict__ g,
                                              const float* __restrict__ u,
                                              __bf16* __restrict__ out, int n4) {
    int i = blockIdx.x * 256 + threadIdx.x;
    int stride = gridDim.x * 256;
    for (; i < n4; i += stride) {
        float4 gv = ((const float4*)g)[i];
        float4 uv = ((const float4*)u)[i];
        bf16x4 o4;
        o4[0] = (__bf16)(gv.x / (1.f + __expf(-gv.x)) * uv.x);
        o4[1] = (__bf16)(gv.y / (1.f + __expf(-gv.y)) * uv.y);
        o4[2] = (__bf16)(gv.z / (1.f + __expf(-gv.z)) * uv.z);
        o4[3] = (__bf16)(gv.w / (1.f + __expf(-gv.w)) * uv.w);
        *(bf16x4*)&out[(size_t)i * 4] = o4;
    }
}

// ---------------- RoPE (rotate-half) on q and k in place ----------------
__global__ __launch_bounds__(256) void k_rope(float* __restrict__ q, float* __restrict__ k) {
    int s  = blockIdx.x;
    int hs = blockIdx.y * 4 + (threadIdx.x >> 6);   // 0..19
    int d  = threadIdx.x & 63;
    float* p = (hs < NH) ? q + ((size_t)s * NH + hs) * HD
                         : k + ((size_t)s * NKV + (hs - NH)) * HD;
    int j = d & 31;
    float inv = exp2f(-(float)(2 * j) * (13.287712379549449f / 64.0f));
    float ang = (float)s * inv;
    float sn, c;
    __sincosf(ang, &sn, &c);
    float xv = p[d];
    float other = (d < 32) ? -p[d + 32] : p[d - 32];   // wave-lockstep safe
    p[d] = xv * c + other * sn;
}

// ---------------- attention scores + causal softmax ----------------
// causal chunk-skip: only chunks c <= (qt*16+15)/64 are computed; masked
// positions are written as exact 0 so k_ctx can consume full chunks.
__global__ __launch_bounds__(256) void k_scores(const float* __restrict__ q,
                                                const float* __restrict__ k,
                                                float* __restrict__ attn) {
    int qt = blockIdx.x;
    int h  = blockIdx.y;
    int kvh = h >> 2;
    __shared__ float qs[16][68];
    __shared__ float ks[64][68];
    __shared__ float sc[16][528];
    int t = threadIdx.x;
    { int row = t >> 4; int c4 = (t & 15) << 2;
      *(float4*)&qs[row][c4] = *(const float4*)&q[(size_t)(qt*16 + row) * H + h * HD + c4]; }
    const int cmax = (qt * 16 + 15) >> 6;
    for (int c = 0; c <= cmax; ++c) {
        #pragma unroll
        for (int i = 0; i < 4; ++i) {
            int id = t + i * 256; int row = id >> 4; int c4 = (id & 15) << 2;
            *(float4*)&ks[row][c4] = *(const float4*)&k[(size_t)(c*64 + row) * KVD + kvh * HD + c4];
        }
        __syncthreads();
        int r  = t >> 4;
        int cc = (t & 15) << 2;
        float4 acc = make_float4(0.f, 0.f, 0.f, 0.f);
        #pragma unroll
        for (int kk = 0; kk < 64; kk += 4) {
            float4 a = *(const float4*)&qs[r][kk];
            acc.x += dot4(a, *(const float4*)&ks[cc + 0][kk]);
            acc.y += dot4(a, *(const float4*)&ks[cc + 1][kk]);
            acc.z += dot4(a, *(const float4*)&ks[cc + 2][kk]);
            acc.w += dot4(a, *(const float4*)&ks[cc + 3][kk]);
        }
        acc.x *= 0.125f; acc.y *= 0.125f; acc.z *= 0.125f; acc.w *= 0.125f;
        *(float4*)&sc[r][c * 64 + cc] = acc;
        __syncthreads();
    }
    int r = t >> 4, lane = t & 15;
    int qpos = qt * 16 + r;
    float mx = -1e30f;
    for (int c = lane; c <= qpos; c += 16) mx = fmaxf(mx, sc[r][c]);
    #pragma unroll
    for (int o = 8; o > 0; o >>= 1) mx = fmaxf(mx, __shfl_xor(mx, o, 16));
    float sum = 0.f;
    for (int c = lane; c <= qpos; c += 16) {
        float e = __expf(sc[r][c] - mx);
        sc[r][c] = e; sum += e;
    }
    #pragma unroll
    for (int o = 8; o > 0; o >>= 1) sum += __shfl_xor(sum, o, 16);
    float inv = 1.0f / sum;
    for (int c = lane; c < SEQ; c += 16)
        attn[((size_t)h * SEQ + qpos) * SEQ + c] = (c <= qpos) ? sc[r][c] * inv : 0.f;
}

// ---------------- ctx = attn @ v -> bf16 (16-row q tiles, chunk-skip) ----
__global__ __launch_bounds__(256) void k_ctx(const float* __restrict__ attn,
                                             const float* __restrict__ v,
                                             __bf16* __restrict__ ctx) {
    int qt = blockIdx.x, h = blockIdx.y, kvh = h >> 2;
    __shared__ float as_[16][68];
    __shared__ float vs[64][68];
    int t = threadIdx.x;
    int row = t >> 4;
    int col = (t & 15) * 4;
    float acc0 = 0.f, acc1 = 0.f, acc2 = 0.f, acc3 = 0.f;
    const int cmax = (qt * 16 + 15) >> 6;
    for (int c = 0; c <= cmax; ++c) {
        { int r2 = t >> 4; int c4 = (t & 15) << 2;
          *(float4*)&as_[r2][c4] = *(const float4*)&attn[((size_t)h*SEQ + qt*16 + r2) * SEQ + c*64 + c4]; }
        #pragma unroll
        for (int i = 0; i < 4; ++i) {
            int id = t + i * 256; int r2 = id >> 4; int c4 = (id & 15) << 2;
            *(float4*)&vs[r2][c4] = *(const float4*)&v[(size_t)(c*64 + r2) * KVD + kvh * HD + c4];
        }
        __syncthreads();
        #pragma unroll 16
        for (int kk = 0; kk < 64; ++kk) {
            float a = as_[row][kk];
            float4 b = *(const float4*)&vs[kk][col];
            acc0 += a * b.x; acc1 += a * b.y; acc2 += a * b.z; acc3 += a * b.w;
        }
        __syncthreads();
    }
    bf16x4 o4;
    o4[0] = (__bf16)acc0; o4[1] = (__bf16)acc1;
    o4[2] = (__bf16)acc2; o4[3] = (__bf16)acc3;
    *(bf16x4*)&ctx[(size_t)(qt*16 + row) * H + h * HD + col] = o4;
}

// ---------------- host launcher ----------------
extern "C" void kernel_launch(void* const* d_in, const int* in_sizes, int n_in,
                              void* d_out, int out_size, void* d_ws, size_t ws_size,
                              hipStream_t stream) {
    const int*   p_ids   = (const int*)  d_in[0];
    const float* p_embed = (const float*)d_in[1];
    const float* p_cb    = (const float*)d_in[2];
    const int*   p_qidx  = (const int*)  d_in[3];  const float* p_qam = (const float*)d_in[4];
    const float* p_qA    = (const float*)d_in[5];  const float* p_qB  = (const float*)d_in[6];
    const int*   p_kidx  = (const int*)  d_in[7];  const float* p_kam = (const float*)d_in[8];
    const float* p_kA    = (const float*)d_in[9];  const float* p_kB  = (const float*)d_in[10];
    const int*   p_vidx  = (const int*)  d_in[11]; const float* p_vam = (const float*)d_in[12];
    const float* p_vA    = (const float*)d_in[13]; const float* p_vB  = (const float*)d_in[14];
    const int*   p_oidx  = (const int*)  d_in[15]; const float* p_oam = (const float*)d_in[16];
    const float* p_oA    = (const float*)d_in[17]; const float* p_oB  = (const float*)d_in[18];
    const int*   p_gidx  = (const int*)  d_in[19]; const float* p_gam = (const float*)d_in[20];
    const float* p_gA    = (const float*)d_in[21]; const float* p_gB  = (const float*)d_in[22];
    const int*   p_uidx  = (const int*)  d_in[23]; const float* p_uam = (const float*)d_in[24];
    const float* p_uA    = (const float*)d_in[25]; const float* p_uB  = (const float*)d_in[26];
    const int*   p_didx  = (const int*)  d_in[27]; const float* p_dam = (const float*)d_in[28];
    const float* p_dA    = (const float*)d_in[29]; const float* p_dB  = (const float*)d_in[30];
    const float* p_ln1   = (const float*)d_in[31];
    const float* p_ln2   = (const float*)d_in[32];
    const float* p_fn    = (const float*)d_in[33];
    const int*   p_lmidx = (const int*)  d_in[34]; const float* p_lmam = (const float*)d_in[35];

    char* w = (char*)d_ws;
    const size_t MB = 1024 * 1024;
    float*  hbuf  = (float*) (w + 0);          // 512x1024 f32  (2 MB)
    __bf16* xb16  = (__bf16*)(w + 2*MB);       // 512x1024 bf16 (1 MB)
    float*  qb    = (float*) (w + 3*MB);       // 512x1024 f32  (2 MB)
    float*  kb    = (float*) (w + 5*MB);       // 512x256  f32  (0.5 MB)
    float*  vb    = (float*) (w + 5*MB + 512*1024);  // 512x256 f32 (0.5 MB)
    __bf16* ctx16 = (__bf16*)(w + 6*MB);       // 512x1024 bf16 (1 MB)
    float*  attn  = (float*) (w + 7*MB);       // 16x512x512 f32 (16.8 MB)
    __bf16* g16   = (__bf16*)(w + 7*MB);       // alias: 512x2816 bf16 (2.9 MB)
    float*  gatef = (float*) (w + 11*MB);      // alias: 512x2816 f32 (5.5 MB)
    float*  upf   = gatef + (size_t)SEQ*IDIM;  // contiguous: 512x2816 f32

    const GSeg znull = {nullptr, nullptr, nullptr, nullptr, nullptr, 0, 0};
    const size_t mlpB = (size_t)SEQ * IDIM * sizeof(float);

    k_embed<<<SEQ, 256, 0, stream>>>(p_ids, p_embed, hbuf);

    for (int l = 0; l < LAYERS; ++l) {
        const int*   qi  = p_qidx + (size_t)l * H * H;      const float* qa = p_qam + (size_t)l * (H*H/64);
        const float* qAl = p_qA + (size_t)l * RR * H;       const float* qBl = p_qB + (size_t)l * H * RR;
        const int*   ki  = p_kidx + (size_t)l * KVD * H;    const float* ka = p_kam + (size_t)l * (KVD*H/64);
        const float* kAl = p_kA + (size_t)l * RR * H;       const float* kBl = p_kB + (size_t)l * KVD * RR;
        const int*   vi  = p_vidx + (size_t)l * KVD * H;    const float* va = p_vam + (size_t)l * (KVD*H/64);
        const float* vAl = p_vA + (size_t)l * RR * H;       const float* vBl = p_vB + (size_t)l * KVD * RR;
        const int*   oi  = p_oidx + (size_t)l * H * H;      const float* oa = p_oam + (size_t)l * (H*H/64);
        const float* oAl = p_oA + (size_t)l * RR * H;       const float* oBl = p_oB + (size_t)l * H * RR;
        const int*   gi  = p_gidx + (size_t)l * IDIM * H;   const float* ga = p_gam + (size_t)l * (IDIM*H/64);
        const float* gAl = p_gA + (size_t)l * RR * H;       const float* gBl = p_gB + (size_t)l * IDIM * RR;
        const int*   ui  = p_uidx + (size_t)l * IDIM * H;   const float* ua = p_uam + (size_t)l * (IDIM*H/64);
        const float* uAl = p_uA + (size_t)l * RR * H;       const float* uBl = p_uB + (size_t)l * IDIM * RR;
        const int*   di  = p_didx + (size_t)l * H * IDIM;   const float* da = p_dam + (size_t)l * (H*IDIM/64);
        const float* dAl = p_dA + (size_t)l * RR * IDIM;    const float* dBl = p_dB + (size_t)l * H * RR;

        // ---- attention block ----
        k_rmsnorm<<<SEQ, 256, 0, stream>>>(hbuf, p_ln1 + (size_t)l * H, xb16);
        hipMemsetAsync(qb, 0, 3*MB, stream);   // qb+kb+vb contiguous
        {
            GSeg sq = {qi, qa, qAl, qBl, qb, H,   8};
            GSeg sk = {ki, ka, kAl, kBl, kb, KVD, 2};
            GSeg sv = {vi, va, vAl, vBl, vb, KVD, 2};
            k_gemm<3,true,0,8><<<dim3(4,16,8), 512, 0, stream>>>(
                xb16, p_cb, sq, sk, sv, H, 12);
        }
        k_rope<<<dim3(SEQ, 5), 256, 0, stream>>>(qb, kb);
        k_scores<<<dim3(SEQ/16, NH), 256, 0, stream>>>(qb, kb, attn);
        k_ctx<<<dim3(SEQ/16, NH), 256, 0, stream>>>(attn, vb, ctx16);
        {
            GSeg so = {oi, oa, oAl, oBl, hbuf, H, 8};
            k_gemm<1,true,1,8><<<dim3(4,8,8), 512, 0, stream>>>(
                ctx16, p_cb, so, znull, znull, H, 8);
        }

        // ---- MLP block ----
        k_rmsnorm<<<SEQ, 256, 0, stream>>>(hbuf, p_ln2 + (size_t)l * H, xb16);
        hipMemsetAsync(gatef, 0, 2 * mlpB, stream);   // gate+up contiguous
        {
            GSeg sg = {gi, ga, gAl, gBl, gatef, IDIM, 22};
            GSeg su = {ui, ua, uAl, uBl, upf,   IDIM, 22};
            // grid-y = 48 = 8*ceil(44/8): swizzle groups must be complete!
            k_gemm<2,true,0,4><<<dim3(4,48,4), 512, 0, stream>>>(
                xb16, p_cb, sg, su, znull, H, 44);
        }
        k_silu<<<1024, 256, 0, stream>>>(gatef, upf, g16, SEQ * IDIM / 4);
        {
            GSeg sd = {di, da, dAl, dBl, hbuf, H, 8};
            k_gemm<1,true,1,11><<<dim3(4,8,11), 512, 0, stream>>>(
                g16, p_cb, sd, znull, znull, IDIM, 8);
        }
    }

    // final norm + quantized lm_head (no LoRA): LDS-staged, 8-wave low-reg
    k_rmsnorm<<<SEQ, 256, 0, stream>>>(hbuf, p_fn, xb16);
    {
        GSeg sl = {p_lmidx, p_lmam, nullptr, nullptr, (float*)d_out, VOCAB, 250};
        k_gemm<1,false,0,1><<<dim3(4,256), 512, 0, stream>>>(
            xb16, p_cb, sl, znull, znull, H, 250);
    }
}